// Round 5
// baseline (687.173 us; speedup 1.0000x reference)
//
#include <hip/hip_runtime.h>
#include <math.h>

__device__ __forceinline__ float silu(float x) { return x / (1.0f + __expf(-x)); }

// ---------------- Kernel 1: per-node precompute (unchanged) ----------------
__global__ __launch_bounds__(320) void node_pre_kernel(
    const float* __restrict__ nf, const float* __restrict__ na,
    const float* __restrict__ w0, const float* __restrict__ w1,
    const float* __restrict__ scw0, const float* __restrict__ scw1,
    float* __restrict__ y, float* __restrict__ sc)
{
  __shared__ float snf[128];
  __shared__ float sna[4];
  const int n = blockIdx.x;
  const int t = threadIdx.x;
  if (t < 128) snf[t] = nf[n * 128 + t];
  if (t >= 128 && t < 132) sna[t - 128] = na[n * 4 + (t - 128)];
  __syncthreads();
  const float inv_sqrt32 = 0.17677669529663687f;
  const float sc_norm    = 0.08838834764831843f;  // 1/sqrt(32*4)
  if (t < 32) {
    const int w = t;
    float acc = 0.f;
    for (int u = 0; u < 32; ++u) acc += snf[u] * w0[u * 32 + w];
    y[n * 128 + w] = acc * inv_sqrt32;
  } else if (t < 128) {
    const int q = t - 32, w = q / 3, i = q - w * 3;
    float acc = 0.f;
    for (int u = 0; u < 32; ++u) acc += snf[32 + u * 3 + i] * w1[u * 32 + w];
    y[n * 128 + 32 + w * 3 + i] = acc * inv_sqrt32;
  } else if (t < 192) {
    const int w = t - 128;
    float acc = 0.f;
    for (int k = 0; k < 128; ++k) acc += snf[k >> 2] * sna[k & 3] * scw0[k * 64 + w];
    sc[n * 160 + w] = acc * sc_norm;
  } else if (t < 288) {
    const int q = t - 192, w = q / 3, i = q - w * 3;
    float acc = 0.f;
    for (int k = 0; k < 128; ++k) acc += snf[32 + (k >> 2) * 3 + i] * sna[k & 3] * scw1[k * 32 + w];
    sc[n * 160 + 64 + w * 3 + i] = acc * sc_norm;
  }
}

// ---------------- CSR build ----------------
__global__ __launch_bounds__(256) void hist_kernel(const int* __restrict__ eidx,
                                                   int* __restrict__ counts, int E)
{
  const int e = blockIdx.x * 256 + threadIdx.x;
  if (e < E) atomicAdd(&counts[eidx[E + e]], 1);
}

__global__ __launch_bounds__(1024) void scan_kernel(const int* __restrict__ counts,
                                                    int* __restrict__ offsets,
                                                    int* __restrict__ cursor, int N)
{
  __shared__ int part[1024];
  const int t = threadIdx.x;
  const int per = (N + 1023) / 1024;
  const int base = t * per;
  int s = 0;
  for (int k = 0; k < per; ++k) { int idx = base + k; if (idx < N) s += counts[idx]; }
  part[t] = s;
  __syncthreads();
  for (int off = 1; off < 1024; off <<= 1) {
    int v = part[t];
    if (t >= off) v += part[t - off];
    __syncthreads();
    part[t] = v;
    __syncthreads();
  }
  int run = (t == 0) ? 0 : part[t - 1];
  for (int k = 0; k < per; ++k) {
    int idx = base + k;
    if (idx < N) { offsets[idx] = run; cursor[idx] = run; run += counts[idx]; }
  }
  if (t == 1023) offsets[N] = run;
}

__global__ __launch_bounds__(256) void scatter_kernel(const int* __restrict__ eidx,
                                                      int* __restrict__ cursor,
                                                      int* __restrict__ elist, int E)
{
  const int e = blockIdx.x * 256 + threadIdx.x;
  if (e >= E) return;
  const int dst = eidx[E + e];
  const int slot = atomicAdd(&cursor[dst], 1);
  elist[slot] = e;
}

// ---------------- Kernel 2a: tiled layers 1+2 -> h2 into wbuf[slot][0:64] ----
// TILE=128 edges/block. h1 staged transposed [k][128] so phase-2 reads b128.
__global__ __launch_bounds__(256) void edge_h2_kernel(
    const float* __restrict__ eemb, const float* __restrict__ fw1,
    const float* __restrict__ fw2, const int* __restrict__ elist,
    float* __restrict__ wbuf, int E)
{
  __shared__ __align__(16) float w1L[512];      // [k<64][r<8]
  __shared__ __align__(16) float w2L[4096];     // [k<64][o<64]
  __shared__ __align__(16) float embL[1024];    // [e<128][r<8]
  __shared__ __align__(16) float h1L[8192];     // [k<64][e<128]
  __shared__ int sEid[128];
  const int t = threadIdx.x;
  const int base = blockIdx.x * 128;

  for (int x = t; x < 512; x += 256)  w1L[x] = fw1[(x & 7) * 64 + (x >> 3)];
  for (int x = t; x < 4096; x += 256) w2L[x] = fw2[x];
  if (t < 128) sEid[t] = (base + t < E) ? elist[base + t] : 0;
  __syncthreads();

  {  // stage emb (gathered by eid)
    const int e = t >> 1, half = t & 1;
    const int eid = sEid[e];
    *(float4*)(embL + e * 8 + half * 4) =
        *(const float4*)(eemb + (size_t)eid * 8 + half * 4);
  }
  __syncthreads();

  // ---- phase 1: h1[k][e] ----
  {
    const int e = t & 127, kg = t >> 7;        // kg in {0,1}
    const float4 em0 = *(const float4*)(embL + e * 8);
    const float4 em1 = *(const float4*)(embL + e * 8 + 4);
    const float inv_sqrt8 = 0.35355339059327373f;
#pragma unroll
    for (int kk = 0; kk < 32; ++kk) {
      const int k = kg * 32 + kk;
      const float4 wa = *(const float4*)(w1L + k * 8);
      const float4 wb = *(const float4*)(w1L + k * 8 + 4);
      const float a = em0.x * wa.x + em0.y * wa.y + em0.z * wa.z + em0.w * wa.w
                    + em1.x * wb.x + em1.y * wb.y + em1.z * wb.z + em1.w * wb.w;
      h1L[k * 128 + e] = silu(a * inv_sqrt8);
    }
  }
  __syncthreads();

  // ---- phase 2: C[128e][64o] = h1^T * w2, micro-tile 4e x 8o ----
  {
    const int og = t & 7, eg = t >> 3;
    const int o0 = og * 8, e0 = eg * 4;
    float acc[4][8];
#pragma unroll
    for (int i = 0; i < 4; ++i)
#pragma unroll
      for (int j = 0; j < 8; ++j) acc[i][j] = 0.f;

    for (int k = 0; k < 64; ++k) {
      const float4 hv = *(const float4*)(h1L + k * 128 + e0);
      const float4 w0v = *(const float4*)(w2L + k * 64 + o0);
      const float4 w1v = *(const float4*)(w2L + k * 64 + o0 + 4);
      const float h[4] = {hv.x, hv.y, hv.z, hv.w};
      const float w[8] = {w0v.x, w0v.y, w0v.z, w0v.w, w1v.x, w1v.y, w1v.z, w1v.w};
#pragma unroll
      for (int i = 0; i < 4; ++i)
#pragma unroll
        for (int j = 0; j < 8; ++j) acc[i][j] += h[i] * w[j];
    }
#pragma unroll
    for (int i = 0; i < 4; ++i) {
      const int slot = base + e0 + i;
      if (slot < E) {
        float4 v;
        v.x = silu(acc[i][0] * 0.125f); v.y = silu(acc[i][1] * 0.125f);
        v.z = silu(acc[i][2] * 0.125f); v.w = silu(acc[i][3] * 0.125f);
        *(float4*)(wbuf + (size_t)slot * 128 + o0) = v;
        v.x = silu(acc[i][4] * 0.125f); v.y = silu(acc[i][5] * 0.125f);
        v.z = silu(acc[i][6] * 0.125f); v.w = silu(acc[i][7] * 0.125f);
        *(float4*)(wbuf + (size_t)slot * 128 + o0 + 4) = v;
      }
    }
  }
}

// ---------------- Kernel 2b: tiled layer 3, in-place on wbuf rows ----------
// TILE=128 edges/block. h2 staged transposed [k][128]; micro-tile 4e x 16c.
__global__ __launch_bounds__(256) void edge_w3_kernel(
    const float* __restrict__ fw3, float* __restrict__ wbuf, int E)
{
  __shared__ __align__(16) float w3L[8192];   // [k<64][c<128]
  __shared__ __align__(16) float h2L[8192];   // [k<64][e<128]
  const int t = threadIdx.x;
  const int base = blockIdx.x * 128;

  for (int x = t; x < 8192; x += 256) w3L[x] = fw3[x];
#pragma unroll
  for (int p = 0; p < 8; ++p) {       // stage h2, transposing
    const int idx = p * 256 + t;
    const int row = idx >> 4, c4 = (idx & 15) * 4;
    const int slot = base + row;
    float4 v = make_float4(0.f, 0.f, 0.f, 0.f);
    if (slot < E) v = *(const float4*)(wbuf + (size_t)slot * 128 + c4);
    h2L[(c4 + 0) * 128 + row] = v.x;
    h2L[(c4 + 1) * 128 + row] = v.y;
    h2L[(c4 + 2) * 128 + row] = v.z;
    h2L[(c4 + 3) * 128 + row] = v.w;
  }
  __syncthreads();

  const int og = t & 7, eg = t >> 3;
  const int c0 = og * 16, e0 = eg * 4;
  float acc[4][16];
#pragma unroll
  for (int i = 0; i < 4; ++i)
#pragma unroll
    for (int j = 0; j < 16; ++j) acc[i][j] = 0.f;

  for (int k = 0; k < 64; ++k) {
    const float4 hv = *(const float4*)(h2L + k * 128 + e0);
    const float h[4] = {hv.x, hv.y, hv.z, hv.w};
    float w[16];
#pragma unroll
    for (int j = 0; j < 16; j += 4) {
      const float4 wv = *(const float4*)(w3L + k * 128 + c0 + j);
      w[j] = wv.x; w[j + 1] = wv.y; w[j + 2] = wv.z; w[j + 3] = wv.w;
    }
#pragma unroll
    for (int i = 0; i < 4; ++i)
#pragma unroll
      for (int j = 0; j < 16; ++j) acc[i][j] += h[i] * w[j];
  }
#pragma unroll
  for (int i = 0; i < 4; ++i) {
    const int slot = base + e0 + i;
    if (slot < E) {
#pragma unroll
      for (int j = 0; j < 16; j += 4) {
        float4 v;
        v.x = acc[i][j] * 0.125f;     v.y = acc[i][j + 1] * 0.125f;
        v.z = acc[i][j + 2] * 0.125f; v.w = acc[i][j + 3] * 0.125f;
        *(float4*)(wbuf + (size_t)slot * 128 + c0 + j) = v;
      }
    }
  }
}

// ---------------- Kernel 3: 8 nodes/block gather + lin2 + gate + residual ---
__global__ __launch_bounds__(256) void seg_gather_out_kernel(
    const float* __restrict__ nf, const float* __restrict__ wbuf,
    const float* __restrict__ y, const float* __restrict__ sc,
    const float* __restrict__ l2w0, const float* __restrict__ l2w1,
    const int* __restrict__ offsets, const int* __restrict__ elist,
    const int* __restrict__ eidx, const float* __restrict__ eattr,
    const int* __restrict__ avgp, float* __restrict__ out, int N, int E)
{
  __shared__ float m8[8][256];
  __shared__ float w0L[4096];   // l2w0 [u<64][w<64]
  __shared__ float w1Ls[2048];  // l2w1 [u<64][w<32]
  __shared__ float so0[64];
  __shared__ float so1[96];
  const int t = threadIdx.x;
  for (int x = t; x < 4096; x += 256) w0L[x] = l2w0[x];
  for (int x = t; x < 2048; x += 256) w1Ls[x] = l2w1[x];

  // per-thread output-column mapping (proven in R3/R4)
  int wi, yi0, yi1, yi2, selA;  // selA: 0=e0,1=e1x,2=e1y,3=e1z
  bool is1 = false;
  if (t < 32) {            // o_s0[u]
    wi = t; yi0 = yi1 = yi2 = t; selA = 0;
  } else if (t < 64) {     // o_s1[u]
    const int u = t - 32;
    wi = 96 + u; yi0 = 32 + 3 * u; yi1 = yi0 + 1; yi2 = yi0 + 2; selA = 1; is1 = true;
  } else if (t < 160) {    // o_v0[u][i]
    const int q = t - 64, u = q / 3, i = q - u * 3;
    wi = 32 + u; yi0 = yi1 = yi2 = u; selA = 1 + i;
  } else {                 // o_v1[u][i]
    const int q = t - 160, u = q / 3, i = q - u * 3;
    wi = 64 + u; yi0 = yi1 = yi2 = 32 + 3 * u + i; selA = 0;
  }
  const float inv_sqrt3 = 0.5773502691896258f;
  const int node0 = blockIdx.x * 8;

  // ---- gather phase: contiguous slot range per node ----
  for (int nn = 0; nn < 8; ++nn) {
    const int n = node0 + nn;
    if (n >= N) break;
    const int beg = offsets[n], end = offsets[n + 1];
    float accv = 0.f;
    for (int s = beg; s < end; ++s) {
      const int eid = elist[s];
      const int src = eidx[eid];
      const float4 ea = *(const float4*)(eattr + (size_t)eid * 4);
      const float* wr = wbuf + (size_t)s * 128;
      const float* yr = y + (size_t)src * 128;
      const float A = (selA == 0) ? ea.x : (selA == 1) ? ea.y
                    : (selA == 2) ? ea.z : ea.w;
      if (is1) {
        accv += wr[wi] * (A * yr[yi0] + ea.z * yr[yi1] + ea.w * yr[yi2]);
      } else {
        accv += wr[wi] * (A * yr[yi0]);
      }
    }
    if (is1) accv *= inv_sqrt3;
    m8[nn][t] = accv;
  }
  __syncthreads();

  const float inv_avg = rsqrtf((float)(*avgp));
  const float scl = 0.125f * inv_avg;

  // ---- epilogue per node ----
  for (int nn = 0; nn < 8; ++nn) {
    const int n = node0 + nn;
    if (n >= N) break;
    if (t < 64) {
      float acc = 0.f;
      for (int u = 0; u < 64; ++u) acc += m8[nn][u] * w0L[u * 64 + t];
      so0[t] = acc * scl + sc[(size_t)n * 160 + t];
    } else if (t < 160) {
      const int q = t - 64, w = q / 3, i = q - w * 3;
      float acc = 0.f;
      for (int u = 0; u < 64; ++u) acc += m8[nn][64 + u * 3 + i] * w1Ls[u * 32 + w];
      so1[w * 3 + i] = acc * scl + sc[(size_t)n * 160 + 64 + w * 3 + i];
    }
    __syncthreads();
    if (t < 32) {
      out[(size_t)n * 128 + t] = nf[(size_t)n * 128 + t] + silu(so0[t]);
    } else if (t < 128) {
      const int q = t - 32, w = q / 3, i = q - w * 3;
      out[(size_t)n * 128 + t] = nf[(size_t)n * 128 + t] + silu(so0[32 + w]) * so1[w * 3 + i];
    }
    __syncthreads();
  }
}

extern "C" void kernel_launch(void* const* d_in, const int* in_sizes, int n_in,
                              void* d_out, int out_size, void* d_ws, size_t ws_size,
                              hipStream_t stream)
{
  const float* nf    = (const float*)d_in[0];
  const float* na    = (const float*)d_in[1];
  const float* eattr = (const float*)d_in[2];
  const float* eemb  = (const float*)d_in[3];
  const float* l1w0  = (const float*)d_in[4];
  const float* l1w1  = (const float*)d_in[5];
  const float* fw1   = (const float*)d_in[6];
  const float* fw2   = (const float*)d_in[7];
  const float* fw3   = (const float*)d_in[8];
  const float* l2w0  = (const float*)d_in[9];
  const float* l2w1  = (const float*)d_in[10];
  const float* scw0  = (const float*)d_in[11];
  const float* scw1  = (const float*)d_in[12];
  const int*   eidx  = (const int*)d_in[13];
  const int*   avgp  = (const int*)d_in[14];

  const int N = in_sizes[0] / 128;
  const int E = in_sizes[2] / 4;

  // Same byte layout as R3/R4 (known to fit in ws_size).
  float* y       = (float*)d_ws;                    // N*128
  float* sc      = y + (size_t)N * 128;             // N*160
  float* wbuf    = sc + (size_t)N * 160;            // E*128  (slot-major, sorted by dst)
  int*   counts  = (int*)(wbuf + (size_t)E * 128);  // N
  int*   offsets = counts + N;                      // N+1
  int*   cursor  = offsets + N + 1;                 // N
  int*   elist   = cursor + N;                      // E (slot -> eid)

  hipMemsetAsync(counts, 0, (size_t)N * sizeof(int), stream);
  node_pre_kernel<<<N, 320, 0, stream>>>(nf, na, l1w0, l1w1, scw0, scw1, y, sc);
  hist_kernel<<<(E + 255) / 256, 256, 0, stream>>>(eidx, counts, E);
  scan_kernel<<<1, 1024, 0, stream>>>(counts, offsets, cursor, N);
  scatter_kernel<<<(E + 255) / 256, 256, 0, stream>>>(eidx, cursor, elist, E);
  edge_h2_kernel<<<(E + 127) / 128, 256, 0, stream>>>(eemb, fw1, fw2, elist, wbuf, E);
  edge_w3_kernel<<<(E + 127) / 128, 256, 0, stream>>>(fw3, wbuf, E);
  seg_gather_out_kernel<<<(N + 7) / 8, 256, 0, stream>>>(nf, wbuf, y, sc, l2w0, l2w1,
                                                         offsets, elist, eidx, eattr,
                                                         avgp, (float*)d_out, N, E);
}

// Round 7
// 433.862 us; speedup vs baseline: 1.5839x; 1.5839x over previous
//
#include <hip/hip_runtime.h>
#include <math.h>

__device__ __forceinline__ float silu(float x) { return x / (1.0f + __expf(-x)); }

// ---------------- Kernel 1: per-node precompute (unchanged) ----------------
__global__ __launch_bounds__(320) void node_pre_kernel(
    const float* __restrict__ nf, const float* __restrict__ na,
    const float* __restrict__ w0, const float* __restrict__ w1,
    const float* __restrict__ scw0, const float* __restrict__ scw1,
    float* __restrict__ y, float* __restrict__ sc)
{
  __shared__ float snf[128];
  __shared__ float sna[4];
  const int n = blockIdx.x;
  const int t = threadIdx.x;
  if (t < 128) snf[t] = nf[n * 128 + t];
  if (t >= 128 && t < 132) sna[t - 128] = na[n * 4 + (t - 128)];
  __syncthreads();
  const float inv_sqrt32 = 0.17677669529663687f;
  const float sc_norm    = 0.08838834764831843f;  // 1/sqrt(32*4)
  if (t < 32) {
    const int w = t;
    float acc = 0.f;
    for (int u = 0; u < 32; ++u) acc += snf[u] * w0[u * 32 + w];
    y[n * 128 + w] = acc * inv_sqrt32;
  } else if (t < 128) {
    const int q = t - 32, w = q / 3, i = q - w * 3;
    float acc = 0.f;
    for (int u = 0; u < 32; ++u) acc += snf[32 + u * 3 + i] * w1[u * 32 + w];
    y[n * 128 + 32 + w * 3 + i] = acc * inv_sqrt32;
  } else if (t < 192) {
    const int w = t - 128;
    float acc = 0.f;
    for (int k = 0; k < 128; ++k) acc += snf[k >> 2] * sna[k & 3] * scw0[k * 64 + w];
    sc[n * 160 + w] = acc * sc_norm;
  } else if (t < 288) {
    const int q = t - 192, w = q / 3, i = q - w * 3;
    float acc = 0.f;
    for (int k = 0; k < 128; ++k) acc += snf[32 + (k >> 2) * 3 + i] * sna[k & 3] * scw1[k * 32 + w];
    sc[n * 160 + 64 + w * 3 + i] = acc * sc_norm;
  }
}

// ---------------- CSR build (unchanged) ----------------
__global__ __launch_bounds__(256) void hist_kernel(const int* __restrict__ eidx,
                                                   int* __restrict__ counts, int E)
{
  const int e = blockIdx.x * 256 + threadIdx.x;
  if (e < E) atomicAdd(&counts[eidx[E + e]], 1);
}

__global__ __launch_bounds__(1024) void scan_kernel(const int* __restrict__ counts,
                                                    int* __restrict__ offsets,
                                                    int* __restrict__ cursor, int N)
{
  __shared__ int part[1024];
  const int t = threadIdx.x;
  const int per = (N + 1023) / 1024;
  const int base = t * per;
  int s = 0;
  for (int k = 0; k < per; ++k) { int idx = base + k; if (idx < N) s += counts[idx]; }
  part[t] = s;
  __syncthreads();
  for (int off = 1; off < 1024; off <<= 1) {
    int v = part[t];
    if (t >= off) v += part[t - off];
    __syncthreads();
    part[t] = v;
    __syncthreads();
  }
  int run = (t == 0) ? 0 : part[t - 1];
  for (int k = 0; k < per; ++k) {
    int idx = base + k;
    if (idx < N) { offsets[idx] = run; cursor[idx] = run; run += counts[idx]; }
  }
  if (t == 1023) offsets[N] = run;
}

__global__ __launch_bounds__(256) void scatter_kernel(const int* __restrict__ eidx,
                                                      int* __restrict__ cursor,
                                                      int* __restrict__ elist, int E)
{
  const int e = blockIdx.x * 256 + threadIdx.x;
  if (e >= E) return;
  const int dst = eidx[E + e];
  const int slot = atomicAdd(&cursor[dst], 1);
  elist[slot] = e;
}

// ---------------- Kernel 2a: tiled layers 1+2 (unchanged from R5) ----------
__global__ __launch_bounds__(256) void edge_h2_kernel(
    const float* __restrict__ eemb, const float* __restrict__ fw1,
    const float* __restrict__ fw2, const int* __restrict__ elist,
    float* __restrict__ wbuf, int E)
{
  __shared__ __align__(16) float w1L[512];      // [k<64][r<8]
  __shared__ __align__(16) float w2L[4096];     // [k<64][o<64]
  __shared__ __align__(16) float embL[1024];    // [e<128][r<8]
  __shared__ __align__(16) float h1L[8192];     // [k<64][e<128]
  __shared__ int sEid[128];
  const int t = threadIdx.x;
  const int base = blockIdx.x * 128;

  for (int x = t; x < 512; x += 256)  w1L[x] = fw1[(x & 7) * 64 + (x >> 3)];
  for (int x = t; x < 4096; x += 256) w2L[x] = fw2[x];
  if (t < 128) sEid[t] = (base + t < E) ? elist[base + t] : 0;
  __syncthreads();

  {  // stage emb (gathered by eid)
    const int e = t >> 1, half = t & 1;
    const int eid = sEid[e];
    *(float4*)(embL + e * 8 + half * 4) =
        *(const float4*)(eemb + (size_t)eid * 8 + half * 4);
  }
  __syncthreads();

  {  // phase 1: h1[k][e]
    const int e = t & 127, kg = t >> 7;
    const float4 em0 = *(const float4*)(embL + e * 8);
    const float4 em1 = *(const float4*)(embL + e * 8 + 4);
    const float inv_sqrt8 = 0.35355339059327373f;
#pragma unroll
    for (int kk = 0; kk < 32; ++kk) {
      const int k = kg * 32 + kk;
      const float4 wa = *(const float4*)(w1L + k * 8);
      const float4 wb = *(const float4*)(w1L + k * 8 + 4);
      const float a = em0.x * wa.x + em0.y * wa.y + em0.z * wa.z + em0.w * wa.w
                    + em1.x * wb.x + em1.y * wb.y + em1.z * wb.z + em1.w * wb.w;
      h1L[k * 128 + e] = silu(a * inv_sqrt8);
    }
  }
  __syncthreads();

  {  // phase 2: micro-tile 4e x 8o
    const int og = t & 7, eg = t >> 3;
    const int o0 = og * 8, e0 = eg * 4;
    float acc[4][8];
#pragma unroll
    for (int i = 0; i < 4; ++i)
#pragma unroll
      for (int j = 0; j < 8; ++j) acc[i][j] = 0.f;

    for (int k = 0; k < 64; ++k) {
      const float4 hv = *(const float4*)(h1L + k * 128 + e0);
      const float4 w0v = *(const float4*)(w2L + k * 64 + o0);
      const float4 w1v = *(const float4*)(w2L + k * 64 + o0 + 4);
      const float h[4] = {hv.x, hv.y, hv.z, hv.w};
      const float w[8] = {w0v.x, w0v.y, w0v.z, w0v.w, w1v.x, w1v.y, w1v.z, w1v.w};
#pragma unroll
      for (int i = 0; i < 4; ++i)
#pragma unroll
        for (int j = 0; j < 8; ++j) acc[i][j] += h[i] * w[j];
    }
#pragma unroll
    for (int i = 0; i < 4; ++i) {
      const int slot = base + e0 + i;
      if (slot < E) {
        float4 v;
        v.x = silu(acc[i][0] * 0.125f); v.y = silu(acc[i][1] * 0.125f);
        v.z = silu(acc[i][2] * 0.125f); v.w = silu(acc[i][3] * 0.125f);
        *(float4*)(wbuf + (size_t)slot * 128 + o0) = v;
        v.x = silu(acc[i][4] * 0.125f); v.y = silu(acc[i][5] * 0.125f);
        v.z = silu(acc[i][6] * 0.125f); v.w = silu(acc[i][7] * 0.125f);
        *(float4*)(wbuf + (size_t)slot * 128 + o0 + 4) = v;
      }
    }
  }
}

// ---------------- Kernel 2b: tiled layer 3 (unchanged from R5) -------------
__global__ __launch_bounds__(256) void edge_w3_kernel(
    const float* __restrict__ fw3, float* __restrict__ wbuf, int E)
{
  __shared__ __align__(16) float w3L[8192];   // [k<64][c<128]
  __shared__ __align__(16) float h2L[8192];   // [k<64][e<128]
  const int t = threadIdx.x;
  const int base = blockIdx.x * 128;

  for (int x = t; x < 8192; x += 256) w3L[x] = fw3[x];
#pragma unroll
  for (int p = 0; p < 8; ++p) {       // stage h2, transposing
    const int idx = p * 256 + t;
    const int row = idx >> 4, c4 = (idx & 15) * 4;
    const int slot = base + row;
    float4 v = make_float4(0.f, 0.f, 0.f, 0.f);
    if (slot < E) v = *(const float4*)(wbuf + (size_t)slot * 128 + c4);
    h2L[(c4 + 0) * 128 + row] = v.x;
    h2L[(c4 + 1) * 128 + row] = v.y;
    h2L[(c4 + 2) * 128 + row] = v.z;
    h2L[(c4 + 3) * 128 + row] = v.w;
  }
  __syncthreads();

  const int og = t & 7, eg = t >> 3;
  const int c0 = og * 16, e0 = eg * 4;
  float acc[4][16];
#pragma unroll
  for (int i = 0; i < 4; ++i)
#pragma unroll
    for (int j = 0; j < 16; ++j) acc[i][j] = 0.f;

  for (int k = 0; k < 64; ++k) {
    const float4 hv = *(const float4*)(h2L + k * 128 + e0);
    const float h[4] = {hv.x, hv.y, hv.z, hv.w};
    float w[16];
#pragma unroll
    for (int j = 0; j < 16; j += 4) {
      const float4 wv = *(const float4*)(w3L + k * 128 + c0 + j);
      w[j] = wv.x; w[j + 1] = wv.y; w[j + 2] = wv.z; w[j + 3] = wv.w;
    }
#pragma unroll
    for (int i = 0; i < 4; ++i)
#pragma unroll
      for (int j = 0; j < 16; ++j) acc[i][j] += h[i] * w[j];
  }
#pragma unroll
  for (int i = 0; i < 4; ++i) {
    const int slot = base + e0 + i;
    if (slot < E) {
#pragma unroll
      for (int j = 0; j < 16; j += 4) {
        float4 v;
        v.x = acc[i][j] * 0.125f;     v.y = acc[i][j + 1] * 0.125f;
        v.z = acc[i][j + 2] * 0.125f; v.w = acc[i][j + 3] * 0.125f;
        *(float4*)(wbuf + (size_t)slot * 128 + c0 + j) = v;
      }
    }
  }
}

// ---------------- Kernel 3: 1 node/block, chunked cooperative staging ------
__global__ __launch_bounds__(256) void gather_out_kernel(
    const float* __restrict__ nf, const float* __restrict__ wbuf,
    const float* __restrict__ y, const float* __restrict__ sc,
    const float* __restrict__ l2w0, const float* __restrict__ l2w1,
    const int* __restrict__ offsets, const int* __restrict__ elist,
    const int* __restrict__ eidx, const float* __restrict__ eattr,
    const int* __restrict__ avgp, float* __restrict__ out, int N, int E)
{
  constexpr int CH = 32;
  __shared__ int sSrc[CH];
  __shared__ __align__(16) float eaL[CH][4];
  __shared__ __align__(16) float yL[CH][128];
  __shared__ float sm[256];
  __shared__ float so0[64];
  __shared__ float so1[96];
  const int n = blockIdx.x, t = threadIdx.x;

  // per-thread output-component mapping (proven R3-R5)
  int wi, yi0, yi1, yi2, selA;  // selA: 0=e0,1=e1x,2=e1y,3=e1z
  bool is1 = false;
  if (t < 32) {            // o_s0[u]
    wi = t; yi0 = yi1 = yi2 = t; selA = 0;
  } else if (t < 64) {     // o_s1[u]
    const int u = t - 32;
    wi = 96 + u; yi0 = 32 + 3 * u; yi1 = yi0 + 1; yi2 = yi0 + 2; selA = 1; is1 = true;
  } else if (t < 160) {    // o_v0[u][i]
    const int q = t - 64, u = q / 3, i = q - u * 3;
    wi = 32 + u; yi0 = yi1 = yi2 = u; selA = 1 + i;
  } else {                 // o_v1[u][i]
    const int q = t - 160, u = q / 3, i = q - u * 3;
    wi = 64 + u; yi0 = yi1 = yi2 = 32 + 3 * u + i; selA = 0;
  }

  const int beg = offsets[n], end = offsets[n + 1];
  float accv = 0.f;

  for (int c0 = beg; c0 < end; c0 += CH) {
    const int cn = min(CH, end - c0);
    // ---- stage indices + eattr (single chain, 32 threads) ----
    if (t < CH) {
      int srcv = 0;
      float4 eav = make_float4(0.f, 0.f, 0.f, 0.f);
      if (t < cn) {
        const int eid = elist[c0 + t];
        srcv = eidx[eid];
        eav = *(const float4*)(eattr + (size_t)eid * 4);
      }
      sSrc[t] = srcv;
      *(float4*)&eaL[t][0] = eav;
    }
    __syncthreads();
    // ---- stage y rows cooperatively (32 rows x 32 float4 = 4 passes) ----
#pragma unroll
    for (int p = 0; p < 4; ++p) {
      const int lin = p * 256 + t;          // float4 index
      const int row = lin >> 5, f4 = lin & 31;
      if (row < cn) {
        *(float4*)&yL[row][f4 * 4] =
            *(const float4*)(y + (size_t)sSrc[row] * 128 + f4 * 4);
      }
    }
    __syncthreads();
    // ---- inner loop: pure stream + LDS (batched x4) ----
    for (int i0 = 0; i0 < cn; i0 += 4) {
      float wq[4];
#pragma unroll
      for (int q = 0; q < 4; ++q) {
        const int i = i0 + q;
        wq[q] = (i < cn) ? wbuf[(size_t)(c0 + i) * 128 + wi] : 0.f;   // FIXED: wi not t
      }
#pragma unroll
      for (int q = 0; q < 4; ++q) {
        const int i = i0 + q;
        if (i < cn) {
          const float* yr = yL[i];
          const float A = eaL[i][selA];
          if (is1) {
            accv += wq[q] * (A * yr[yi0] + eaL[i][2] * yr[yi1] + eaL[i][3] * yr[yi2]);
          } else {
            accv += wq[q] * (A * yr[yi0]);
          }
        }
      }
    }
    __syncthreads();   // protect yL before next chunk overwrites
  }

  const float inv_sqrt3 = 0.5773502691896258f;
  if (is1) accv *= inv_sqrt3;
  sm[t] = accv;
  __syncthreads();

  const float inv_avg = rsqrtf((float)(*avgp));
  const float scl = 0.125f * inv_avg;
  if (t < 64) {
    float acc = 0.f;
    for (int u = 0; u < 64; ++u) acc += sm[u] * l2w0[u * 64 + t];
    so0[t] = acc * scl + sc[(size_t)n * 160 + t];
  } else if (t < 160) {
    const int q = t - 64, w = q / 3, i = q - w * 3;
    float acc = 0.f;
    for (int u = 0; u < 64; ++u) acc += sm[64 + u * 3 + i] * l2w1[u * 32 + w];
    so1[w * 3 + i] = acc * scl + sc[(size_t)n * 160 + 64 + w * 3 + i];
  }
  __syncthreads();
  if (t < 32) {
    out[(size_t)n * 128 + t] = nf[(size_t)n * 128 + t] + silu(so0[t]);
  } else if (t < 128) {
    const int q = t - 32, w = q / 3, i = q - w * 3;
    out[(size_t)n * 128 + t] = nf[(size_t)n * 128 + t] + silu(so0[32 + w]) * so1[w * 3 + i];
  }
}

extern "C" void kernel_launch(void* const* d_in, const int* in_sizes, int n_in,
                              void* d_out, int out_size, void* d_ws, size_t ws_size,
                              hipStream_t stream)
{
  const float* nf    = (const float*)d_in[0];
  const float* na    = (const float*)d_in[1];
  const float* eattr = (const float*)d_in[2];
  const float* eemb  = (const float*)d_in[3];
  const float* l1w0  = (const float*)d_in[4];
  const float* l1w1  = (const float*)d_in[5];
  const float* fw1   = (const float*)d_in[6];
  const float* fw2   = (const float*)d_in[7];
  const float* fw3   = (const float*)d_in[8];
  const float* l2w0  = (const float*)d_in[9];
  const float* l2w1  = (const float*)d_in[10];
  const float* scw0  = (const float*)d_in[11];
  const float* scw1  = (const float*)d_in[12];
  const int*   eidx  = (const int*)d_in[13];
  const int*   avgp  = (const int*)d_in[14];

  const int N = in_sizes[0] / 128;
  const int E = in_sizes[2] / 4;

  // Same byte layout as R3/R4/R5 (known to fit in ws_size).
  float* y       = (float*)d_ws;                    // N*128
  float* sc      = y + (size_t)N * 128;             // N*160
  float* wbuf    = sc + (size_t)N * 160;            // E*128  (slot-major, sorted by dst)
  int*   counts  = (int*)(wbuf + (size_t)E * 128);  // N
  int*   offsets = counts + N;                      // N+1
  int*   cursor  = offsets + N + 1;                 // N
  int*   elist   = cursor + N;                      // E (slot -> eid)

  hipMemsetAsync(counts, 0, (size_t)N * sizeof(int), stream);
  node_pre_kernel<<<N, 320, 0, stream>>>(nf, na, l1w0, l1w1, scw0, scw1, y, sc);
  hist_kernel<<<(E + 255) / 256, 256, 0, stream>>>(eidx, counts, E);
  scan_kernel<<<1, 1024, 0, stream>>>(counts, offsets, cursor, N);
  scatter_kernel<<<(E + 255) / 256, 256, 0, stream>>>(eidx, cursor, elist, E);
  edge_h2_kernel<<<(E + 127) / 128, 256, 0, stream>>>(eemb, fw1, fw2, elist, wbuf, E);
  edge_w3_kernel<<<(E + 127) / 128, 256, 0, stream>>>(fw3, wbuf, E);
  gather_out_kernel<<<N, 256, 0, stream>>>(nf, wbuf, y, sc, l2w0, l2w1,
                                           offsets, elist, eidx, eattr, avgp,
                                           (float*)d_out, N, E);
}

// Round 8
// 432.774 us; speedup vs baseline: 1.5878x; 1.0025x over previous
//
#include <hip/hip_runtime.h>
#include <math.h>

__device__ __forceinline__ float silu(float x) { return x / (1.0f + __expf(-x)); }

// ---------------- Kernel 1: per-node precompute (unchanged) ----------------
__global__ __launch_bounds__(320) void node_pre_kernel(
    const float* __restrict__ nf, const float* __restrict__ na,
    const float* __restrict__ w0, const float* __restrict__ w1,
    const float* __restrict__ scw0, const float* __restrict__ scw1,
    float* __restrict__ y, float* __restrict__ sc)
{
  __shared__ float snf[128];
  __shared__ float sna[4];
  const int n = blockIdx.x;
  const int t = threadIdx.x;
  if (t < 128) snf[t] = nf[n * 128 + t];
  if (t >= 128 && t < 132) sna[t - 128] = na[n * 4 + (t - 128)];
  __syncthreads();
  const float inv_sqrt32 = 0.17677669529663687f;
  const float sc_norm    = 0.08838834764831843f;  // 1/sqrt(32*4)
  if (t < 32) {
    const int w = t;
    float acc = 0.f;
    for (int u = 0; u < 32; ++u) acc += snf[u] * w0[u * 32 + w];
    y[n * 128 + w] = acc * inv_sqrt32;
  } else if (t < 128) {
    const int q = t - 32, w = q / 3, i = q - w * 3;
    float acc = 0.f;
    for (int u = 0; u < 32; ++u) acc += snf[32 + u * 3 + i] * w1[u * 32 + w];
    y[n * 128 + 32 + w * 3 + i] = acc * inv_sqrt32;
  } else if (t < 192) {
    const int w = t - 128;
    float acc = 0.f;
    for (int k = 0; k < 128; ++k) acc += snf[k >> 2] * sna[k & 3] * scw0[k * 64 + w];
    sc[n * 160 + w] = acc * sc_norm;
  } else if (t < 288) {
    const int q = t - 192, w = q / 3, i = q - w * 3;
    float acc = 0.f;
    for (int k = 0; k < 128; ++k) acc += snf[32 + (k >> 2) * 3 + i] * sna[k & 3] * scw1[k * 32 + w];
    sc[n * 160 + 64 + w * 3 + i] = acc * sc_norm;
  }
}

// ---------------- CSR build (unchanged) ----------------
__global__ __launch_bounds__(256) void hist_kernel(const int* __restrict__ eidx,
                                                   int* __restrict__ counts, int E)
{
  const int e = blockIdx.x * 256 + threadIdx.x;
  if (e < E) atomicAdd(&counts[eidx[E + e]], 1);
}

__global__ __launch_bounds__(1024) void scan_kernel(const int* __restrict__ counts,
                                                    int* __restrict__ offsets,
                                                    int* __restrict__ cursor, int N)
{
  __shared__ int part[1024];
  const int t = threadIdx.x;
  const int per = (N + 1023) / 1024;
  const int base = t * per;
  int s = 0;
  for (int k = 0; k < per; ++k) { int idx = base + k; if (idx < N) s += counts[idx]; }
  part[t] = s;
  __syncthreads();
  for (int off = 1; off < 1024; off <<= 1) {
    int v = part[t];
    if (t >= off) v += part[t - off];
    __syncthreads();
    part[t] = v;
    __syncthreads();
  }
  int run = (t == 0) ? 0 : part[t - 1];
  for (int k = 0; k < per; ++k) {
    int idx = base + k;
    if (idx < N) { offsets[idx] = run; cursor[idx] = run; run += counts[idx]; }
  }
  if (t == 1023) offsets[N] = run;
}

__global__ __launch_bounds__(256) void scatter_kernel(const int* __restrict__ eidx,
                                                      int* __restrict__ cursor,
                                                      int* __restrict__ elist, int E)
{
  const int e = blockIdx.x * 256 + threadIdx.x;
  if (e >= E) return;
  const int dst = eidx[E + e];
  const int slot = atomicAdd(&cursor[dst], 1);
  elist[slot] = e;
}

// ---------------- Kernel 2a: tiled layers 1+2 -> h2T (register transpose) --
// h2T layout: wbuf[tile*16384 + 8192 + o*128 + e]  (upper half of tile region)
__global__ __launch_bounds__(256) void edge_h2_kernel(
    const float* __restrict__ eemb, const float* __restrict__ fw1,
    const float* __restrict__ fw2, const int* __restrict__ elist,
    float* __restrict__ wbuf, int E)
{
  __shared__ __align__(16) float w1L[512];      // [k<64][r<8]
  __shared__ __align__(16) float w2L[4096];     // [k<64][o<64]
  __shared__ __align__(16) float embL[1024];    // [e<128][r<8]
  __shared__ __align__(16) float h1L[8192];     // [k<64][e<128]
  __shared__ int sEid[128];
  const int t = threadIdx.x;
  const int base = blockIdx.x * 128;

  for (int x = t; x < 512; x += 256)  w1L[x] = fw1[(x & 7) * 64 + (x >> 3)];
  for (int x = t; x < 4096; x += 256) w2L[x] = fw2[x];
  if (t < 128) sEid[t] = (base + t < E) ? elist[base + t] : 0;
  __syncthreads();

  {  // stage emb (gathered by eid)
    const int e = t >> 1, half = t & 1;
    const int eid = sEid[e];
    *(float4*)(embL + e * 8 + half * 4) =
        *(const float4*)(eemb + (size_t)eid * 8 + half * 4);
  }
  __syncthreads();

  {  // phase 1: h1[k][e]
    const int e = t & 127, kg = t >> 7;
    const float4 em0 = *(const float4*)(embL + e * 8);
    const float4 em1 = *(const float4*)(embL + e * 8 + 4);
    const float inv_sqrt8 = 0.35355339059327373f;
#pragma unroll
    for (int kk = 0; kk < 32; ++kk) {
      const int k = kg * 32 + kk;
      const float4 wa = *(const float4*)(w1L + k * 8);
      const float4 wb = *(const float4*)(w1L + k * 8 + 4);
      const float a = em0.x * wa.x + em0.y * wa.y + em0.z * wa.z + em0.w * wa.w
                    + em1.x * wb.x + em1.y * wb.y + em1.z * wb.z + em1.w * wb.w;
      h1L[k * 128 + e] = silu(a * inv_sqrt8);
    }
  }
  __syncthreads();

  {  // phase 2: micro-tile 4e x 8o; write h2 TRANSPOSED into h2T
    const int og = t & 7, eg = t >> 3;
    const int o0 = og * 8, e0 = eg * 4;
    float acc[4][8];
#pragma unroll
    for (int i = 0; i < 4; ++i)
#pragma unroll
      for (int j = 0; j < 8; ++j) acc[i][j] = 0.f;

    for (int k = 0; k < 64; ++k) {
      const float4 hv = *(const float4*)(h1L + k * 128 + e0);
      const float4 w0v = *(const float4*)(w2L + k * 64 + o0);
      const float4 w1v = *(const float4*)(w2L + k * 64 + o0 + 4);
      const float h[4] = {hv.x, hv.y, hv.z, hv.w};
      const float w[8] = {w0v.x, w0v.y, w0v.z, w0v.w, w1v.x, w1v.y, w1v.z, w1v.w};
#pragma unroll
      for (int i = 0; i < 4; ++i)
#pragma unroll
        for (int j = 0; j < 8; ++j) acc[i][j] += h[i] * w[j];
    }
    float* h2t = wbuf + (size_t)blockIdx.x * 16384 + 8192;
#pragma unroll
    for (int j = 0; j < 8; ++j) {
      float4 v;
      v.x = silu(acc[0][j] * 0.125f);
      v.y = silu(acc[1][j] * 0.125f);
      v.z = silu(acc[2][j] * 0.125f);
      v.w = silu(acc[3][j] * 0.125f);
      *(float4*)(h2t + (size_t)(o0 + j) * 128 + e0) = v;
    }
  }
}

// ---------------- Kernel 2b: tiled layer 3, conflict-free LDS --------------
// h2L staged by straight copy from h2T (no transpose); w3L bank-swizzled.
__global__ __launch_bounds__(256) void edge_w3_kernel(
    const float* __restrict__ fw3, float* __restrict__ wbuf, int E)
{
  __shared__ __align__(16) float w3L[64 * 144];  // [k][swz(c)], stride 144
  __shared__ __align__(16) float h2L[8192];      // [k<64][e<128]
  const int t = threadIdx.x;
  const int base = blockIdx.x * 128;
  const float* h2t = wbuf + (size_t)blockIdx.x * 16384 + 8192;

  for (int x = t; x < 8192; x += 256) {
    const int k = x >> 7, c = x & 127;
    w3L[k * 144 + c + ((c >> 5) << 2)] = fw3[x];
  }
  for (int x4 = t; x4 < 2048; x4 += 256)
    ((float4*)h2L)[x4] = ((const float4*)h2t)[x4];
  __syncthreads();

  const int og = t & 7, eg = t >> 3;
  const int c0 = og * 16, e0 = eg * 4;
  const int cswz = c0 + ((c0 >> 5) << 2);
  float acc[4][16];
#pragma unroll
  for (int i = 0; i < 4; ++i)
#pragma unroll
    for (int j = 0; j < 16; ++j) acc[i][j] = 0.f;

  for (int k = 0; k < 64; ++k) {
    const float4 hv = *(const float4*)(h2L + k * 128 + e0);
    const float h[4] = {hv.x, hv.y, hv.z, hv.w};
    float w[16];
#pragma unroll
    for (int j = 0; j < 4; ++j) {
      const float4 wv = *(const float4*)(w3L + k * 144 + cswz + j * 4);
      w[j * 4] = wv.x; w[j * 4 + 1] = wv.y; w[j * 4 + 2] = wv.z; w[j * 4 + 3] = wv.w;
    }
#pragma unroll
    for (int i = 0; i < 4; ++i)
#pragma unroll
      for (int j = 0; j < 16; ++j) acc[i][j] += h[i] * w[j];
  }
#pragma unroll
  for (int i = 0; i < 4; ++i) {
    const int slot = base + e0 + i;
    if (slot < E) {
#pragma unroll
      for (int j = 0; j < 16; j += 4) {
        float4 v;
        v.x = acc[i][j] * 0.125f;     v.y = acc[i][j + 1] * 0.125f;
        v.z = acc[i][j + 2] * 0.125f; v.w = acc[i][j + 3] * 0.125f;
        *(float4*)(wbuf + (size_t)slot * 128 + c0 + j) = v;
      }
    }
  }
}

// ---------------- Kernel 3: 1 node/block, chunked cooperative staging ------
__global__ __launch_bounds__(256) void gather_out_kernel(
    const float* __restrict__ nf, const float* __restrict__ wbuf,
    const float* __restrict__ y, const float* __restrict__ sc,
    const float* __restrict__ l2w0, const float* __restrict__ l2w1,
    const int* __restrict__ offsets, const int* __restrict__ elist,
    const int* __restrict__ eidx, const float* __restrict__ eattr,
    const int* __restrict__ avgp, float* __restrict__ out, int N, int E)
{
  constexpr int CH = 32;
  __shared__ int sSrc[CH];
  __shared__ __align__(16) float eaL[CH][4];
  __shared__ __align__(16) float yL[CH][128];
  __shared__ float sm[256];
  __shared__ float so0[64];
  __shared__ float so1[96];
  const int n = blockIdx.x, t = threadIdx.x;

  int wi, yi0, yi1, yi2, selA;  // selA: 0=e0,1=e1x,2=e1y,3=e1z
  bool is1 = false;
  if (t < 32) {            // o_s0[u]
    wi = t; yi0 = yi1 = yi2 = t; selA = 0;
  } else if (t < 64) {     // o_s1[u]
    const int u = t - 32;
    wi = 96 + u; yi0 = 32 + 3 * u; yi1 = yi0 + 1; yi2 = yi0 + 2; selA = 1; is1 = true;
  } else if (t < 160) {    // o_v0[u][i]
    const int q = t - 64, u = q / 3, i = q - u * 3;
    wi = 32 + u; yi0 = yi1 = yi2 = u; selA = 1 + i;
  } else {                 // o_v1[u][i]
    const int q = t - 160, u = q / 3, i = q - u * 3;
    wi = 64 + u; yi0 = yi1 = yi2 = 32 + 3 * u + i; selA = 0;
  }

  const int beg = offsets[n], end = offsets[n + 1];
  float accv = 0.f;

  for (int c0 = beg; c0 < end; c0 += CH) {
    const int cn = min(CH, end - c0);
    if (t < CH) {
      int srcv = 0;
      float4 eav = make_float4(0.f, 0.f, 0.f, 0.f);
      if (t < cn) {
        const int eid = elist[c0 + t];
        srcv = eidx[eid];
        eav = *(const float4*)(eattr + (size_t)eid * 4);
      }
      sSrc[t] = srcv;
      *(float4*)&eaL[t][0] = eav;
    }
    __syncthreads();
#pragma unroll
    for (int p = 0; p < 4; ++p) {
      const int lin = p * 256 + t;          // float4 index
      const int row = lin >> 5, f4 = lin & 31;
      if (row < cn) {
        *(float4*)&yL[row][f4 * 4] =
            *(const float4*)(y + (size_t)sSrc[row] * 128 + f4 * 4);
      }
    }
    __syncthreads();
    for (int i0 = 0; i0 < cn; i0 += 4) {
      float wq[4];
#pragma unroll
      for (int q = 0; q < 4; ++q) {
        const int i = i0 + q;
        wq[q] = (i < cn) ? wbuf[(size_t)(c0 + i) * 128 + wi] : 0.f;
      }
#pragma unroll
      for (int q = 0; q < 4; ++q) {
        const int i = i0 + q;
        if (i < cn) {
          const float* yr = yL[i];
          const float A = eaL[i][selA];
          if (is1) {
            accv += wq[q] * (A * yr[yi0] + eaL[i][2] * yr[yi1] + eaL[i][3] * yr[yi2]);
          } else {
            accv += wq[q] * (A * yr[yi0]);
          }
        }
      }
    }
    __syncthreads();   // protect yL before next chunk overwrites
  }

  const float inv_sqrt3 = 0.5773502691896258f;
  if (is1) accv *= inv_sqrt3;
  sm[t] = accv;
  __syncthreads();

  const float inv_avg = rsqrtf((float)(*avgp));
  const float scl = 0.125f * inv_avg;
  if (t < 64) {
    float acc = 0.f;
    for (int u = 0; u < 64; ++u) acc += sm[u] * l2w0[u * 64 + t];
    so0[t] = acc * scl + sc[(size_t)n * 160 + t];
  } else if (t < 160) {
    const int q = t - 64, w = q / 3, i = q - w * 3;
    float acc = 0.f;
    for (int u = 0; u < 64; ++u) acc += sm[64 + u * 3 + i] * l2w1[u * 32 + w];
    so1[w * 3 + i] = acc * scl + sc[(size_t)n * 160 + 64 + w * 3 + i];
  }
  __syncthreads();
  if (t < 32) {
    out[(size_t)n * 128 + t] = nf[(size_t)n * 128 + t] + silu(so0[t]);
  } else if (t < 128) {
    const int q = t - 32, w = q / 3, i = q - w * 3;
    out[(size_t)n * 128 + t] = nf[(size_t)n * 128 + t] + silu(so0[32 + w]) * so1[w * 3 + i];
  }
}

extern "C" void kernel_launch(void* const* d_in, const int* in_sizes, int n_in,
                              void* d_out, int out_size, void* d_ws, size_t ws_size,
                              hipStream_t stream)
{
  const float* nf    = (const float*)d_in[0];
  const float* na    = (const float*)d_in[1];
  const float* eattr = (const float*)d_in[2];
  const float* eemb  = (const float*)d_in[3];
  const float* l1w0  = (const float*)d_in[4];
  const float* l1w1  = (const float*)d_in[5];
  const float* fw1   = (const float*)d_in[6];
  const float* fw2   = (const float*)d_in[7];
  const float* fw3   = (const float*)d_in[8];
  const float* l2w0  = (const float*)d_in[9];
  const float* l2w1  = (const float*)d_in[10];
  const float* scw0  = (const float*)d_in[11];
  const float* scw1  = (const float*)d_in[12];
  const int*   eidx  = (const int*)d_in[13];
  const int*   avgp  = (const int*)d_in[14];

  const int N = in_sizes[0] / 128;
  const int E = in_sizes[2] / 4;
  const int Epad = ((E + 127) / 128) * 128;   // tile-region bound (E=320000 -> Epad=E)

  float* y       = (float*)d_ws;                       // N*128
  float* sc      = y + (size_t)N * 128;                // N*160
  float* wbuf    = sc + (size_t)N * 160;               // Epad*128 (w rows + per-tile h2T)
  int*   counts  = (int*)(wbuf + (size_t)Epad * 128);  // N
  int*   offsets = counts + N;                         // N+1
  int*   cursor  = offsets + N + 1;                    // N
  int*   elist   = cursor + N;                         // E (slot -> eid)

  hipMemsetAsync(counts, 0, (size_t)N * sizeof(int), stream);
  node_pre_kernel<<<N, 320, 0, stream>>>(nf, na, l1w0, l1w1, scw0, scw1, y, sc);
  hist_kernel<<<(E + 255) / 256, 256, 0, stream>>>(eidx, counts, E);
  scan_kernel<<<1, 1024, 0, stream>>>(counts, offsets, cursor, N);
  scatter_kernel<<<(E + 255) / 256, 256, 0, stream>>>(eidx, cursor, elist, E);
  edge_h2_kernel<<<(E + 127) / 128, 256, 0, stream>>>(eemb, fw1, fw2, elist, wbuf, E);
  edge_w3_kernel<<<(E + 127) / 128, 256, 0, stream>>>(fw3, wbuf, E);
  gather_out_kernel<<<N, 256, 0, stream>>>(nf, wbuf, y, sc, l2w0, l2w1,
                                           offsets, elist, eidx, eattr, avgp,
                                           (float*)d_out, N, E);
}

// Round 9
// 397.714 us; speedup vs baseline: 1.7278x; 1.0882x over previous
//
#include <hip/hip_runtime.h>
#include <math.h>

__device__ __forceinline__ float silu(float x) { return x / (1.0f + __expf(-x)); }

// ---------------- Kernel 1: per-node precompute (unchanged) ----------------
__global__ __launch_bounds__(320) void node_pre_kernel(
    const float* __restrict__ nf, const float* __restrict__ na,
    const float* __restrict__ w0, const float* __restrict__ w1,
    const float* __restrict__ scw0, const float* __restrict__ scw1,
    float* __restrict__ y, float* __restrict__ sc)
{
  __shared__ float snf[128];
  __shared__ float sna[4];
  const int n = blockIdx.x;
  const int t = threadIdx.x;
  if (t < 128) snf[t] = nf[n * 128 + t];
  if (t >= 128 && t < 132) sna[t - 128] = na[n * 4 + (t - 128)];
  __syncthreads();
  const float inv_sqrt32 = 0.17677669529663687f;
  const float sc_norm    = 0.08838834764831843f;  // 1/sqrt(32*4)
  if (t < 32) {
    const int w = t;
    float acc = 0.f;
    for (int u = 0; u < 32; ++u) acc += snf[u] * w0[u * 32 + w];
    y[n * 128 + w] = acc * inv_sqrt32;
  } else if (t < 128) {
    const int q = t - 32, w = q / 3, i = q - w * 3;
    float acc = 0.f;
    for (int u = 0; u < 32; ++u) acc += snf[32 + u * 3 + i] * w1[u * 32 + w];
    y[n * 128 + 32 + w * 3 + i] = acc * inv_sqrt32;
  } else if (t < 192) {
    const int w = t - 128;
    float acc = 0.f;
    for (int k = 0; k < 128; ++k) acc += snf[k >> 2] * sna[k & 3] * scw0[k * 64 + w];
    sc[n * 160 + w] = acc * sc_norm;
  } else if (t < 288) {
    const int q = t - 192, w = q / 3, i = q - w * 3;
    float acc = 0.f;
    for (int k = 0; k < 128; ++k) acc += snf[32 + (k >> 2) * 3 + i] * sna[k & 3] * scw1[k * 32 + w];
    sc[n * 160 + 64 + w * 3 + i] = acc * sc_norm;
  }
}

// ---------------- CSR build (unchanged) ----------------
__global__ __launch_bounds__(256) void hist_kernel(const int* __restrict__ eidx,
                                                   int* __restrict__ counts, int E)
{
  const int e = blockIdx.x * 256 + threadIdx.x;
  if (e < E) atomicAdd(&counts[eidx[E + e]], 1);
}

__global__ __launch_bounds__(1024) void scan_kernel(const int* __restrict__ counts,
                                                    int* __restrict__ offsets,
                                                    int* __restrict__ cursor, int N)
{
  __shared__ int part[1024];
  const int t = threadIdx.x;
  const int per = (N + 1023) / 1024;
  const int base = t * per;
  int s = 0;
  for (int k = 0; k < per; ++k) { int idx = base + k; if (idx < N) s += counts[idx]; }
  part[t] = s;
  __syncthreads();
  for (int off = 1; off < 1024; off <<= 1) {
    int v = part[t];
    if (t >= off) v += part[t - off];
    __syncthreads();
    part[t] = v;
    __syncthreads();
  }
  int run = (t == 0) ? 0 : part[t - 1];
  for (int k = 0; k < per; ++k) {
    int idx = base + k;
    if (idx < N) { offsets[idx] = run; cursor[idx] = run; run += counts[idx]; }
  }
  if (t == 1023) offsets[N] = run;
}

__global__ __launch_bounds__(256) void scatter_kernel(const int* __restrict__ eidx,
                                                      int* __restrict__ cursor,
                                                      int* __restrict__ elist, int E)
{
  const int e = blockIdx.x * 256 + threadIdx.x;
  if (e >= E) return;
  const int dst = eidx[E + e];
  const int slot = atomicAdd(&cursor[dst], 1);
  elist[slot] = e;
}

// ---------------- Kernel 2: FUSED 3-layer edge MLP (tile = 128 edges) ------
// Phase A: h1 -> reg3 ([k<64][e<128]).  Phase B: h2 -> registers.
// Handoff: h2 regs -> reg3 (reuse, float4 rows: conflict-optimal), w3 -> reg2
// (swizzled stride 144, proven R8).  Phase C: layer 3 -> wbuf.
__global__ __launch_bounds__(256) void edge_mlp_kernel(
    const float* __restrict__ eemb, const float* __restrict__ fw1,
    const float* __restrict__ fw2, const float* __restrict__ fw3,
    const int* __restrict__ elist, float* __restrict__ wbuf, int E)
{
  __shared__ __align__(16) float w1L[512];    // [k<64][r<8] transposed
  __shared__ __align__(16) float reg2[9216];  // B: w2[64][64] ; C: w3 swz [64][144]
  __shared__ __align__(16) float reg3[8192];  // A/B: h1[k][e] ; C: h2[k][e]
  const int t = threadIdx.x;
  const int base = blockIdx.x * 128;

  for (int x = t; x < 512; x += 256)  w1L[x] = fw1[(x & 7) * 64 + (x >> 3)];
  for (int x = t; x < 4096; x += 256) reg2[x] = fw2[x];

  // per-thread edge (2 threads per edge), emb kept in registers
  const int e = t & 127, kg = t >> 7;
  const int slot0 = base + e;
  const int eid = (slot0 < E) ? elist[slot0] : 0;
  const float4 em0 = *(const float4*)(eemb + (size_t)eid * 8);
  const float4 em1 = *(const float4*)(eemb + (size_t)eid * 8 + 4);
  __syncthreads();

  {  // ---- phase A: h1[k][e], 32 k per thread ----
    const float inv_sqrt8 = 0.35355339059327373f;
#pragma unroll
    for (int kk = 0; kk < 32; ++kk) {
      const int k = kg * 32 + kk;
      const float4 wa = *(const float4*)(w1L + k * 8);
      const float4 wb = *(const float4*)(w1L + k * 8 + 4);
      const float a = em0.x * wa.x + em0.y * wa.y + em0.z * wa.z + em0.w * wa.w
                    + em1.x * wb.x + em1.y * wb.y + em1.z * wb.z + em1.w * wb.w;
      reg3[k * 128 + e] = silu(a * inv_sqrt8);
    }
  }
  __syncthreads();

  const int og = t & 7, eg = t >> 3;
  const int e0 = eg * 4;

  // ---- phase B: h2 micro-tile 4e x 8o into registers ----
  float acc[4][8];
#pragma unroll
  for (int i = 0; i < 4; ++i)
#pragma unroll
    for (int j = 0; j < 8; ++j) acc[i][j] = 0.f;
  {
    const int o0 = og * 8;
    for (int k = 0; k < 64; ++k) {
      const float4 hv  = *(const float4*)(reg3 + k * 128 + e0);
      const float4 w0v = *(const float4*)(reg2 + k * 64 + o0);
      const float4 w1v = *(const float4*)(reg2 + k * 64 + o0 + 4);
      const float h[4] = {hv.x, hv.y, hv.z, hv.w};
      const float w[8] = {w0v.x, w0v.y, w0v.z, w0v.w, w1v.x, w1v.y, w1v.z, w1v.w};
#pragma unroll
      for (int i = 0; i < 4; ++i)
#pragma unroll
        for (int j = 0; j < 8; ++j) acc[i][j] += h[i] * w[j];
    }
  }
  __syncthreads();   // all reg3(h1)/reg2(w2) reads complete

  // ---- handoff: h2 regs -> reg3 rows (b128: 8 words/bank = optimal) ----
#pragma unroll
  for (int j = 0; j < 8; ++j) {
    const int k = og * 8 + j;
    float4 v;
    v.x = silu(acc[0][j] * 0.125f);
    v.y = silu(acc[1][j] * 0.125f);
    v.z = silu(acc[2][j] * 0.125f);
    v.w = silu(acc[3][j] * 0.125f);
    *(float4*)(reg3 + k * 128 + e0) = v;
  }
  // ---- stage w3 swizzled into reg2 (stride 144, +((c>>5)<<2)) ----
  for (int x = t; x < 8192; x += 256) {
    const int k = x >> 7, c = x & 127;
    reg2[k * 144 + c + ((c >> 5) << 2)] = fw3[x];
  }
  __syncthreads();

  // ---- phase C: layer 3 micro-tile 4e x 16c ----
  const int c0 = og * 16;
  const int cswz = c0 + ((c0 >> 5) << 2);
  float accw[4][16];
#pragma unroll
  for (int i = 0; i < 4; ++i)
#pragma unroll
    for (int j = 0; j < 16; ++j) accw[i][j] = 0.f;

  for (int k = 0; k < 64; ++k) {
    const float4 hv = *(const float4*)(reg3 + k * 128 + e0);
    const float h[4] = {hv.x, hv.y, hv.z, hv.w};
    float w[16];
#pragma unroll
    for (int j = 0; j < 4; ++j) {
      const float4 wv = *(const float4*)(reg2 + k * 144 + cswz + j * 4);
      w[j * 4] = wv.x; w[j * 4 + 1] = wv.y; w[j * 4 + 2] = wv.z; w[j * 4 + 3] = wv.w;
    }
#pragma unroll
    for (int i = 0; i < 4; ++i)
#pragma unroll
      for (int j = 0; j < 16; ++j) accw[i][j] += h[i] * w[j];
  }
#pragma unroll
  for (int i = 0; i < 4; ++i) {
    const int slot = base + e0 + i;
    if (slot < E) {
#pragma unroll
      for (int j = 0; j < 16; j += 4) {
        float4 v;
        v.x = accw[i][j] * 0.125f;     v.y = accw[i][j + 1] * 0.125f;
        v.z = accw[i][j + 2] * 0.125f; v.w = accw[i][j + 3] * 0.125f;
        *(float4*)(wbuf + (size_t)slot * 128 + c0 + j) = v;
      }
    }
  }
}

// ---------------- Kernel 3: 1 node/block, chunked cooperative staging ------
__global__ __launch_bounds__(256) void gather_out_kernel(
    const float* __restrict__ nf, const float* __restrict__ wbuf,
    const float* __restrict__ y, const float* __restrict__ sc,
    const float* __restrict__ l2w0, const float* __restrict__ l2w1,
    const int* __restrict__ offsets, const int* __restrict__ elist,
    const int* __restrict__ eidx, const float* __restrict__ eattr,
    const int* __restrict__ avgp, float* __restrict__ out, int N, int E)
{
  constexpr int CH = 32;
  __shared__ int sSrc[CH];
  __shared__ __align__(16) float eaL[CH][4];
  __shared__ __align__(16) float yL[CH][128];
  __shared__ float sm[256];
  __shared__ float so0[64];
  __shared__ float so1[96];
  const int n = blockIdx.x, t = threadIdx.x;

  int wi, yi0, yi1, yi2, selA;  // selA: 0=e0,1=e1x,2=e1y,3=e1z
  bool is1 = false;
  if (t < 32) {            // o_s0[u]
    wi = t; yi0 = yi1 = yi2 = t; selA = 0;
  } else if (t < 64) {     // o_s1[u]
    const int u = t - 32;
    wi = 96 + u; yi0 = 32 + 3 * u; yi1 = yi0 + 1; yi2 = yi0 + 2; selA = 1; is1 = true;
  } else if (t < 160) {    // o_v0[u][i]
    const int q = t - 64, u = q / 3, i = q - u * 3;
    wi = 32 + u; yi0 = yi1 = yi2 = u; selA = 1 + i;
  } else {                 // o_v1[u][i]
    const int q = t - 160, u = q / 3, i = q - u * 3;
    wi = 64 + u; yi0 = yi1 = yi2 = 32 + 3 * u + i; selA = 0;
  }

  const int beg = offsets[n], end = offsets[n + 1];
  float accv = 0.f;

  for (int c0 = beg; c0 < end; c0 += CH) {
    const int cn = min(CH, end - c0);
    if (t < CH) {
      int srcv = 0;
      float4 eav = make_float4(0.f, 0.f, 0.f, 0.f);
      if (t < cn) {
        const int eid = elist[c0 + t];
        srcv = eidx[eid];
        eav = *(const float4*)(eattr + (size_t)eid * 4);
      }
      sSrc[t] = srcv;
      *(float4*)&eaL[t][0] = eav;
    }
    __syncthreads();
#pragma unroll
    for (int p = 0; p < 4; ++p) {
      const int lin = p * 256 + t;          // float4 index
      const int row = lin >> 5, f4 = lin & 31;
      if (row < cn) {
        *(float4*)&yL[row][f4 * 4] =
            *(const float4*)(y + (size_t)sSrc[row] * 128 + f4 * 4);
      }
    }
    __syncthreads();
    for (int i0 = 0; i0 < cn; i0 += 4) {
      float wq[4];
#pragma unroll
      for (int q = 0; q < 4; ++q) {
        const int i = i0 + q;
        wq[q] = (i < cn) ? wbuf[(size_t)(c0 + i) * 128 + wi] : 0.f;
      }
#pragma unroll
      for (int q = 0; q < 4; ++q) {
        const int i = i0 + q;
        if (i < cn) {
          const float* yr = yL[i];
          const float A = eaL[i][selA];
          if (is1) {
            accv += wq[q] * (A * yr[yi0] + eaL[i][2] * yr[yi1] + eaL[i][3] * yr[yi2]);
          } else {
            accv += wq[q] * (A * yr[yi0]);
          }
        }
      }
    }
    __syncthreads();   // protect yL before next chunk overwrites
  }

  const float inv_sqrt3 = 0.5773502691896258f;
  if (is1) accv *= inv_sqrt3;
  sm[t] = accv;
  __syncthreads();

  const float inv_avg = rsqrtf((float)(*avgp));
  const float scl = 0.125f * inv_avg;
  if (t < 64) {
    float acc = 0.f;
    for (int u = 0; u < 64; ++u) acc += sm[u] * l2w0[u * 64 + t];
    so0[t] = acc * scl + sc[(size_t)n * 160 + t];
  } else if (t < 160) {
    const int q = t - 64, w = q / 3, i = q - w * 3;
    float acc = 0.f;
    for (int u = 0; u < 64; ++u) acc += sm[64 + u * 3 + i] * l2w1[u * 32 + w];
    so1[w * 3 + i] = acc * scl + sc[(size_t)n * 160 + 64 + w * 3 + i];
  }
  __syncthreads();
  if (t < 32) {
    out[(size_t)n * 128 + t] = nf[(size_t)n * 128 + t] + silu(so0[t]);
  } else if (t < 128) {
    const int q = t - 32, w = q / 3, i = q - w * 3;
    out[(size_t)n * 128 + t] = nf[(size_t)n * 128 + t] + silu(so0[32 + w]) * so1[w * 3 + i];
  }
}

extern "C" void kernel_launch(void* const* d_in, const int* in_sizes, int n_in,
                              void* d_out, int out_size, void* d_ws, size_t ws_size,
                              hipStream_t stream)
{
  const float* nf    = (const float*)d_in[0];
  const float* na    = (const float*)d_in[1];
  const float* eattr = (const float*)d_in[2];
  const float* eemb  = (const float*)d_in[3];
  const float* l1w0  = (const float*)d_in[4];
  const float* l1w1  = (const float*)d_in[5];
  const float* fw1   = (const float*)d_in[6];
  const float* fw2   = (const float*)d_in[7];
  const float* fw3   = (const float*)d_in[8];
  const float* l2w0  = (const float*)d_in[9];
  const float* l2w1  = (const float*)d_in[10];
  const float* scw0  = (const float*)d_in[11];
  const float* scw1  = (const float*)d_in[12];
  const int*   eidx  = (const int*)d_in[13];
  const int*   avgp  = (const int*)d_in[14];

  const int N = in_sizes[0] / 128;
  const int E = in_sizes[2] / 4;

  // Same byte layout as R3-R5 (known to fit in ws_size).
  float* y       = (float*)d_ws;                    // N*128
  float* sc      = y + (size_t)N * 128;             // N*160
  float* wbuf    = sc + (size_t)N * 160;            // E*128 (slot-major, sorted by dst)
  int*   counts  = (int*)(wbuf + (size_t)E * 128);  // N
  int*   offsets = counts + N;                      // N+1
  int*   cursor  = offsets + N + 1;                 // N
  int*   elist   = cursor + N;                      // E (slot -> eid)

  hipMemsetAsync(counts, 0, (size_t)N * sizeof(int), stream);
  node_pre_kernel<<<N, 320, 0, stream>>>(nf, na, l1w0, l1w1, scw0, scw1, y, sc);
  hist_kernel<<<(E + 255) / 256, 256, 0, stream>>>(eidx, counts, E);
  scan_kernel<<<1, 1024, 0, stream>>>(counts, offsets, cursor, N);
  scatter_kernel<<<(E + 255) / 256, 256, 0, stream>>>(eidx, cursor, elist, E);
  edge_mlp_kernel<<<(E + 127) / 128, 256, 0, stream>>>(eemb, fw1, fw2, fw3, elist, wbuf, E);
  gather_out_kernel<<<N, 256, 0, stream>>>(nf, wbuf, y, sc, l2w0, l2w1,
                                           offsets, elist, eidx, eattr, avgp,
                                           (float*)d_out, N, E);
}